// Round 1
// baseline (594.395 us; speedup 1.0000x reference)
//
#include <hip/hip_runtime.h>

typedef unsigned char  u8;
typedef unsigned short u16;
typedef unsigned int   u32;

#define NN   16384     // nodes
#define EE   262144    // edges
#define RR   9         // relations
#define DIN  384
#define DH   768
#define KSU  3456      // RR*DIN
#define KS   3488      // KSU + 9 cnt cols + pad to 32

typedef float  f32x4 __attribute__((ext_vector_type(4)));
typedef __bf16 b16x8 __attribute__((ext_vector_type(8)));

__device__ __forceinline__ u16 f2bf(float f){
  u32 u = __builtin_bit_cast(u32, f);
  u += 0x7fffu + ((u >> 16) & 1u);          // RNE
  return (u16)(u >> 16);
}
__device__ __forceinline__ float bf2f(u16 h){
  u32 u = ((u32)h) << 16;
  return __builtin_bit_cast(float, u);
}
// async global->LDS, 16B per lane; LDS dest = wave-uniform base + lane*16
__device__ __forceinline__ void gll16(const void* g, void* l){
  __builtin_amdgcn_global_load_lds((const __attribute__((address_space(1))) void*)g,
                                   (__attribute__((address_space(3))) void*)l, 16, 0, 0);
}

// ---------------- CSR build ----------------
__global__ void k_count(const int* __restrict__ dst, int* __restrict__ counts){
  const int e = blockIdx.x*256 + threadIdx.x;
  if (e < EE) atomicAdd(&counts[dst[e]], 1);
}

__global__ __launch_bounds__(1024) void k_scan(const int* __restrict__ counts,
                                               int* __restrict__ starts,
                                               int* __restrict__ cursor){
  __shared__ int tot[1024];
  const int t = threadIdx.x;
  int loc[16]; int s = 0;
  #pragma unroll
  for (int j=0;j<16;j++){ loc[j] = counts[t*16+j]; s += loc[j]; }
  tot[t] = s;
  __syncthreads();
  for (int o=1;o<1024;o<<=1){
    int v = (t>=o) ? tot[t-o] : 0;
    __syncthreads();
    tot[t] += v;
    __syncthreads();
  }
  int run = tot[t] - s;  // exclusive prefix
  #pragma unroll
  for (int j=0;j<16;j++){ starts[t*16+j] = run; cursor[t*16+j] = run; run += loc[j]; }
  if (t == 1023) starts[NN] = run;
}

__global__ void k_place(const int* __restrict__ dst, int* __restrict__ cursor,
                        int* __restrict__ perm){
  const int e = blockIdx.x*256 + threadIdx.x;
  if (e < EE){ const int p = atomicAdd(&cursor[dst[e]], 1); perm[p] = e; }
}

// ---------------- weight conversion to bf16 ----------------
// W_stack[hh][k]: k<3456 -> rel_W[r=k/384][hh][k%384]; 3456..3464 -> rel_b[r][hh]; else 0
__global__ void k_convW1(const float* __restrict__ rW, const float* __restrict__ rb,
                         u16* __restrict__ Wst){
  const int hh = blockIdx.y;
  const int k  = blockIdx.x*256 + threadIdx.x;
  if (k >= KS) return;
  float v;
  if (k < KSU){ const int r = k / DIN; const int d = k - r*DIN;
                v = rW[((long)r*DH + hh)*DIN + d]; }
  else if (k < KSU + RR){ const int r = k - KSU; v = rb[(long)r*DH + hh]; }
  else v = 0.f;
  Wst[(long)hh*KS + k] = f2bf(v);
}

// WB = concat rows [mp_lin_W(768x768); mp_self_W(768x768)], both [out][in] row-major
__global__ void k_convW2(const float* __restrict__ lW, const float* __restrict__ sW,
                         u16* __restrict__ WB){
  const int idx = blockIdx.x*256 + threadIdx.x;  // exactly 1179648 threads
  const float v = (idx < DH*DH) ? lW[idx] : sW[idx - DH*DH];
  WB[idx] = f2bf(v);
}

// ---------------- phase1: per-dst edge aggregation into s ----------------
// s[i, r*384+d] = sum_{e:dst=i,type=r} (dot(x[i],x[src])/nc[r]) * x[src,d]
// s[i, 3456+r]  = sum norm ; s[i, 3465..3487] = 0
__global__ __launch_bounds__(128) void k_phase1(const float* __restrict__ x,
                                                const int* __restrict__ src_arr,
                                                const int* __restrict__ et,
                                                const float* __restrict__ nc,
                                                const int* __restrict__ starts,
                                                const int* __restrict__ perm,
                                                u16* __restrict__ s){
  const int i = blockIdx.x, t = threadIdx.x;
  __shared__ float accs[KSU];   // 13.5 KB
  __shared__ float xd[DIN];
  __shared__ float red[2];
  __shared__ float cacc[RR];
  __shared__ float ncs[RR];
  for (int c=t;c<KSU;c+=128) accs[c] = 0.f;
  xd[t]       = x[(long)i*DIN + t];
  xd[t+128]   = x[(long)i*DIN + 128 + t];
  xd[t+256]   = x[(long)i*DIN + 256 + t];
  if (t < RR){ cacc[t] = 0.f; ncs[t] = nc[t]; }
  __syncthreads();
  const int e0 = starts[i], e1 = starts[i+1];
  for (int p=e0; p<e1; ++p){
    const int e   = perm[p];
    const int src = src_arr[e];
    const int r   = et[e];
    const float* xs = x + (long)src*DIN;
    const float v0 = xs[t], v1 = xs[t+128], v2 = xs[t+256];
    float part = xd[t]*v0 + xd[t+128]*v1 + xd[t+256]*v2;
    #pragma unroll
    for (int o=32;o;o>>=1) part += __shfl_xor(part, o);
    if ((t & 63) == 0) red[t>>6] = part;
    __syncthreads();
    const float norm = (red[0] + red[1]) / ncs[r];
    float* a = accs + r*DIN;
    a[t]     += norm*v0;
    a[t+128] += norm*v1;
    a[t+256] += norm*v2;
    if (t == 0) cacc[r] += norm;
    __syncthreads();
  }
  u16* srow = s + (long)i*KS;
  for (int c=t;c<KS;c+=128){
    const float v = (c < KSU) ? accs[c] : ((c < KSU+RR) ? cacc[c-KSU] : 0.f);
    srow[c] = f2bf(v);
  }
}

// ---------------- m97-style bf16 GEMM: C = A * B^T (both K-major) ----------------
// 128x128 tile, 256 thr = 4 waves (2x2), each 64x64 via 4x4 of mfma 16x16x32
// MODE 0: O0 = relu(C) bf16, stride DH           (gemm1: x1)
// MODE 1: n<768 -> O0 = C+b0[n]; else O1 = C+b1  (gemm2: hm / selfx)
template<int MODE>
__global__ __launch_bounds__(256, 2)
void k_gemm_bt(const u16* __restrict__ A, const u16* __restrict__ B,
               int M, int N, int K,
               u16* __restrict__ O0, u16* __restrict__ O1,
               const float* __restrict__ b0, const float* __restrict__ b1)
{
  __shared__ __align__(16) u16 As[128*32];
  __shared__ __align__(16) u16 Bs[128*32];
  const int t  = threadIdx.x;
  const int wv = t >> 6;
  const int ln = t & 63;
  const int wm = wv >> 1, wn = wv & 1;
  const long m0 = (long)blockIdx.y * 128;
  const long n0 = (long)blockIdx.x * 128;

  const int srow  = ln >> 2;         // staging: lane -> row within 16-row segment
  const int skcol = (ln & 3) * 8;    // k element offset (8 bf16 = 16B)

  f32x4 acc[4][4];
  #pragma unroll
  for (int i=0;i<4;i++)
    #pragma unroll
    for (int j=0;j<4;j++) acc[i][j] = {0.f,0.f,0.f,0.f};

  const int fr = ln & 15, fq = ln >> 4;
  const int nk = K >> 5;
  for (int kb=0; kb<nk; ++kb){
    const long k0 = (long)kb * 32;
    #pragma unroll
    for (int q=0;q<2;q++){
      const int seg = wv*2 + q;
      const int row = seg*16 + srow;
      gll16(A + (m0 + row)*(long)K + k0 + skcol, &As[seg*512]);
      gll16(B + (n0 + row)*(long)K + k0 + skcol, &Bs[seg*512]);
    }
    __syncthreads();
    b16x8 av[4], bv[4];
    #pragma unroll
    for (int i=0;i<4;i++){
      av[i] = *(const b16x8*)&As[(wm*64 + i*16 + fr)*32 + fq*8];
      bv[i] = *(const b16x8*)&Bs[(wn*64 + i*16 + fr)*32 + fq*8];
    }
    #pragma unroll
    for (int i=0;i<4;i++)
      #pragma unroll
      for (int j=0;j<4;j++)
        acc[i][j] = __builtin_amdgcn_mfma_f32_16x16x32_bf16(av[i], bv[j], acc[i][j], 0, 0, 0);
    __syncthreads();
  }

  #pragma unroll
  for (int i=0;i<4;i++){
    #pragma unroll
    for (int j=0;j<4;j++){
      #pragma unroll
      for (int r=0;r<4;r++){
        const long m = m0 + wm*64 + i*16 + fq*4 + r;   // C row = quad*4+reg
        const long n = n0 + wn*64 + j*16 + fr;         // C col = lane&15
        float v = acc[i][j][r];
        if (MODE == 0){
          v = v > 0.f ? v : 0.f;
          O0[m*DH + n] = f2bf(v);
        } else {
          if (n < DH) O0[m*DH + n]      = f2bf(v + b0[n]);
          else        O1[m*DH + (n-DH)] = f2bf(v + b1[n-DH]);
        }
      }
    }
  }
}

// ---------------- phase2: aggr2 + self + relu -> x2 ----------------
__global__ __launch_bounds__(128) void k_phase2(const u16* __restrict__ hm,
                                                const u16* __restrict__ sfx,
                                                const int* __restrict__ src_arr,
                                                const int* __restrict__ starts,
                                                const int* __restrict__ perm,
                                                float* __restrict__ x2){
  const int i = blockIdx.x, t = threadIdx.x;
  float a[6] = {0,0,0,0,0,0};
  const int e0 = starts[i], e1 = starts[i+1];
  for (int p=e0; p<e1; ++p){
    const int e = perm[p];
    const int s = src_arr[e];
    const u16* hr = hm + (long)s*DH;
    #pragma unroll
    for (int j=0;j<6;j++) a[j] += bf2f(hr[t + 128*j]);
  }
  #pragma unroll
  for (int j=0;j<6;j++){
    const int c = t + 128*j;
    float v = a[j] + bf2f(sfx[(long)i*DH + c]);
    x2[(long)i*DH + c] = v > 0.f ? v : 0.f;
  }
}

// ---------------- mean-pool reduce ----------------
__global__ __launch_bounds__(256) void k_reduce(const float* __restrict__ x2,
                                                float* __restrict__ pooled){
  const int b = blockIdx.x, t = threadIdx.x;
  float s0=0.f, s1=0.f, s2=0.f;
  const int r0 = b*64;
  for (int r=r0; r<r0+64; ++r){
    const float* row = x2 + (long)r*DH;
    s0 += row[t]; s1 += row[t+256]; s2 += row[t+512];
  }
  atomicAdd(&pooled[t],     s0);
  atomicAdd(&pooled[t+256], s1);
  atomicAdd(&pooled[t+512], s2);
}

__global__ __launch_bounds__(256) void k_final(const float* __restrict__ pooled,
                                               const float* __restrict__ oW,
                                               const float* __restrict__ ob,
                                               float* __restrict__ out){
  __shared__ float red[256];
  const int t = threadIdx.x;
  for (int c=0;c<5;c++){
    float p = 0.f;
    for (int h=t; h<DH; h+=256) p += pooled[h]*oW[c*DH + h];
    red[t] = p; __syncthreads();
    for (int o=128;o;o>>=1){ if (t<o) red[t]+=red[t+o]; __syncthreads(); }
    if (t == 0) out[c] = red[0]*(1.f/(float)NN) + ob[c];
    __syncthreads();
  }
}

// ---------------- launch ----------------
extern "C" void kernel_launch(void* const* d_in, const int* in_sizes, int n_in,
                              void* d_out, int out_size, void* d_ws, size_t ws_size,
                              hipStream_t stream)
{
  (void)in_sizes; (void)n_in; (void)out_size; (void)ws_size;
  const float* x     = (const float*)d_in[0];
  const int*   ei    = (const int*)  d_in[1];   // [2][E]: row0=src, row1=dst
  const int*   et    = (const int*)  d_in[2];
  const float* relW  = (const float*)d_in[3];
  const float* relb  = (const float*)d_in[4];
  const float* nc    = (const float*)d_in[5];
  const float* linW  = (const float*)d_in[6];
  const float* linb  = (const float*)d_in[7];
  const float* selfW = (const float*)d_in[8];
  const float* selfb = (const float*)d_in[9];
  const float* outW  = (const float*)d_in[10];
  const float* outb  = (const float*)d_in[11];
  float* out = (float*)d_out;

  // workspace layout (256B aligned); hm/selfx/x2 alias S (dead after gemm1)
  u8* w = (u8*)d_ws;
  int*   counts = (int*)(w + 0);              // 64 KB
  int*   starts = (int*)(w + 65536);          // 16385*4
  int*   cursor = (int*)(w + 131328);         // 64 KB
  int*   perm   = (int*)(w + 196864);         // 1 MB
  u16*   Wst    = (u16*)(w + 1245440);        // 768*3488*2  = 5.36 MB
  u16*   WB     = (u16*)(w + 6603008);        // 1536*768*2  = 2.36 MB
  u16*   x1     = (u16*)(w + 8962304);        // 16384*768*2 = 25.2 MB
  float* pooled = (float*)(w + 34128128);     // 3 KB
  u16*   S      = (u16*)(w + 34131200);       // 16384*3488*2 = 114.3 MB
  u16*   hm     = S;                          // alias: 25.2 MB
  u16*   sfx    = (u16*)(w + 34131200 + 25165824);
  float* x2     = (float*)(w + 34131200 + 50331648);  // 50.3 MB (fits in S)

  const int* esrc = ei;
  const int* edst = ei + EE;

  hipMemsetAsync(counts, 0, NN*sizeof(int), stream);
  hipMemsetAsync(pooled, 0, DH*sizeof(float), stream);

  k_count <<<EE/256, 256, 0, stream>>>(edst, counts);
  k_scan  <<<1, 1024, 0, stream>>>(counts, starts, cursor);
  k_place <<<EE/256, 256, 0, stream>>>(edst, cursor, perm);
  k_convW1<<<dim3(14, DH), 256, 0, stream>>>(relW, relb, Wst);
  k_convW2<<<(2*DH*DH)/256, 256, 0, stream>>>(linW, selfW, WB);
  k_phase1<<<NN, 128, 0, stream>>>(x, esrc, et, nc, starts, perm, S);
  k_gemm_bt<0><<<dim3(DH/128, NN/128), 256, 0, stream>>>(
      S, Wst, NN, DH, KS, x1, (u16*)nullptr, (const float*)nullptr, (const float*)nullptr);
  k_gemm_bt<1><<<dim3(2*DH/128, NN/128), 256, 0, stream>>>(
      x1, WB, NN, 2*DH, DH, hm, sfx, linb, selfb);
  k_phase2<<<NN, 128, 0, stream>>>(hm, sfx, esrc, starts, perm, x2);
  k_reduce<<<NN/64, 256, 0, stream>>>(x2, pooled);
  k_final <<<1, 256, 0, stream>>>(pooled, outW, outb, out);
}

// Round 2
// 560.650 us; speedup vs baseline: 1.0602x; 1.0602x over previous
//
#include <hip/hip_runtime.h>

typedef unsigned char  u8;
typedef unsigned short u16;
typedef unsigned int   u32;

#define NN   16384     // nodes
#define EE   262144    // edges
#define RR   9         // relations
#define DIN  384
#define DH   768
#define KSU  3456      // RR*DIN
#define KS   3488      // KSU + 9 cnt cols + pad to 32

typedef float  f32x4 __attribute__((ext_vector_type(4)));
typedef __bf16 b16x8 __attribute__((ext_vector_type(8)));

__device__ __forceinline__ u16 f2bf(float f){
  u32 u = __builtin_bit_cast(u32, f);
  u += 0x7fffu + ((u >> 16) & 1u);          // RNE
  return (u16)(u >> 16);
}
__device__ __forceinline__ float bf2f(u16 h){
  u32 u = ((u32)h) << 16;
  return __builtin_bit_cast(float, u);
}
// async global->LDS, 16B per lane; LDS dest = wave-uniform base + lane*16
__device__ __forceinline__ void gll16(const void* g, void* l){
  __builtin_amdgcn_global_load_lds((const __attribute__((address_space(1))) void*)g,
                                   (__attribute__((address_space(3))) void*)l, 16, 0, 0);
}

// ---------------- CSR build ----------------
__global__ void k_count(const int* __restrict__ dst, int* __restrict__ counts){
  const int e = blockIdx.x*256 + threadIdx.x;
  if (e < EE) atomicAdd(&counts[dst[e]], 1);
}

__global__ __launch_bounds__(1024) void k_scan(const int* __restrict__ counts,
                                               int* __restrict__ starts,
                                               int* __restrict__ cursor){
  __shared__ int tot[1024];
  const int t = threadIdx.x;
  int loc[16]; int s = 0;
  #pragma unroll
  for (int j=0;j<16;j++){ loc[j] = counts[t*16+j]; s += loc[j]; }
  tot[t] = s;
  __syncthreads();
  for (int o=1;o<1024;o<<=1){
    int v = (t>=o) ? tot[t-o] : 0;
    __syncthreads();
    tot[t] += v;
    __syncthreads();
  }
  int run = tot[t] - s;  // exclusive prefix
  #pragma unroll
  for (int j=0;j<16;j++){ starts[t*16+j] = run; cursor[t*16+j] = run; run += loc[j]; }
  if (t == 1023) starts[NN] = run;
}

// scatter edges into CSR order; emit pre-gathered src/dst/rtype arrays
__global__ void k_place(const int* __restrict__ src, const int* __restrict__ dst,
                        const int* __restrict__ et, int* __restrict__ cursor,
                        int* __restrict__ srcp, int* __restrict__ dstp,
                        int* __restrict__ rp){
  const int e = blockIdx.x*256 + threadIdx.x;
  if (e < EE){
    const int p = atomicAdd(&cursor[dst[e]], 1);
    srcp[p] = src[e];
    dstp[p] = dst[e];
    rp[p]   = et[e];
  }
}

// ---------------- weight conversion to bf16 ----------------
// W_stack[hh][k]: k<3456 -> rel_W[r=k/384][hh][k%384]; 3456..3464 -> rel_b[r][hh]; else 0
__global__ void k_convW1(const float* __restrict__ rW, const float* __restrict__ rb,
                         u16* __restrict__ Wst){
  const int hh = blockIdx.y;
  const int k  = blockIdx.x*256 + threadIdx.x;
  if (k >= KS) return;
  float v;
  if (k < KSU){ const int r = k / DIN; const int d = k - r*DIN;
                v = rW[((long)r*DH + hh)*DIN + d]; }
  else if (k < KSU + RR){ const int r = k - KSU; v = rb[(long)r*DH + hh]; }
  else v = 0.f;
  Wst[(long)hh*KS + k] = f2bf(v);
}

// WB = concat rows [mp_lin_W(768x768); mp_self_W(768x768)], both [out][in] row-major
__global__ void k_convW2(const float* __restrict__ lW, const float* __restrict__ sW,
                         u16* __restrict__ WB){
  const int idx = blockIdx.x*256 + threadIdx.x;  // exactly 1179648 threads
  const float v = (idx < DH*DH) ? lW[idx] : sW[idx - DH*DH];
  WB[idx] = f2bf(v);
}

// ---------------- phase1a: edge-parallel dot products ----------------
// one wave per CSR slot p: normp[p] = dot(x[dstp], x[srcp]) / nc[rp]
__global__ __launch_bounds__(256) void k_dots(const float* __restrict__ x,
                                              const int* __restrict__ srcp,
                                              const int* __restrict__ dstp,
                                              const int* __restrict__ rp,
                                              const float* __restrict__ nc,
                                              float* __restrict__ normp){
  const int p = blockIdx.x*4 + (threadIdx.x >> 6);
  const int l = threadIdx.x & 63;
  const float* xs = x + (long)srcp[p]*DIN;
  const float* xd = x + (long)dstp[p]*DIN;
  float s = 0.f;
  #pragma unroll
  for (int j=0;j<6;j++) s += xs[l + 64*j] * xd[l + 64*j];
  #pragma unroll
  for (int o=32;o;o>>=1) s += __shfl_xor(s, o);
  if (l == 0) normp[p] = s / nc[rp[p]];
}

// ---------------- phase1b: sync-free CSR axpy into S ----------------
// s[i, r*384+d] = sum_{p in seg(i)} normp[p] * x[srcp[p], d]; s[i,3456+r] = sum normp
__global__ __launch_bounds__(128) void k_phase1b(const float* __restrict__ x,
                                                 const int* __restrict__ srcp,
                                                 const int* __restrict__ rp,
                                                 const float* __restrict__ normp,
                                                 const int* __restrict__ starts,
                                                 u16* __restrict__ s){
  const int i = blockIdx.x, t = threadIdx.x;
  __shared__ float accs[KSU];   // 13.5 KB
  __shared__ float cacc[RR];
  for (int c=t;c<KSU;c+=128) accs[c] = 0.f;
  if (t < RR) cacc[t] = 0.f;
  __syncthreads();
  const int e0 = starts[i], e1 = starts[i+1];
  for (int p=e0; p<e1; ++p){
    const int   src  = srcp[p];
    const int   r    = rp[p];
    const float norm = normp[p];
    const float* xs = x + (long)src*DIN;
    const float v0 = xs[t], v1 = xs[t+128], v2 = xs[t+256];
    float* a = accs + r*DIN;      // thread t owns LDS cols {t, t+128, t+256} of every r
    a[t]     += norm*v0;
    a[t+128] += norm*v1;
    a[t+256] += norm*v2;
    if (t == 0) cacc[r] += norm;
  }
  __syncthreads();
  u16* srow = s + (long)i*KS;
  for (int c=t;c<KS;c+=128){
    const float v = (c < KSU) ? accs[c] : ((c < KSU+RR) ? cacc[c-KSU] : 0.f);
    srow[c] = f2bf(v);
  }
}

// ---------------- m97-style bf16 GEMM: C = A * B^T (both K-major) ----------------
// 128x128 tile, 256 thr = 4 waves (2x2), each 64x64 via 4x4 of mfma 16x16x32
// MODE 0: O0 = relu(C) bf16, stride DH           (gemm1: x1)
// MODE 1: n<768 -> O0 = C+b0[n]; else O1 = C+b1  (gemm2: hm / selfx)
template<int MODE>
__global__ __launch_bounds__(256, 2)
void k_gemm_bt(const u16* __restrict__ A, const u16* __restrict__ B,
               int M, int N, int K,
               u16* __restrict__ O0, u16* __restrict__ O1,
               const float* __restrict__ b0, const float* __restrict__ b1)
{
  __shared__ __align__(16) u16 As[128*32];
  __shared__ __align__(16) u16 Bs[128*32];
  const int t  = threadIdx.x;
  const int wv = t >> 6;
  const int ln = t & 63;
  const int wm = wv >> 1, wn = wv & 1;
  const long m0 = (long)blockIdx.y * 128;
  const long n0 = (long)blockIdx.x * 128;

  const int srow  = ln >> 2;         // staging: lane -> row within 16-row segment
  const int skcol = (ln & 3) * 8;    // k element offset (8 bf16 = 16B)

  f32x4 acc[4][4];
  #pragma unroll
  for (int i=0;i<4;i++)
    #pragma unroll
    for (int j=0;j<4;j++) acc[i][j] = {0.f,0.f,0.f,0.f};

  const int fr = ln & 15, fq = ln >> 4;
  const int nk = K >> 5;
  for (int kb=0; kb<nk; ++kb){
    const long k0 = (long)kb * 32;
    #pragma unroll
    for (int q=0;q<2;q++){
      const int seg = wv*2 + q;
      const int row = seg*16 + srow;
      gll16(A + (m0 + row)*(long)K + k0 + skcol, &As[seg*512]);
      gll16(B + (n0 + row)*(long)K + k0 + skcol, &Bs[seg*512]);
    }
    __syncthreads();
    b16x8 av[4], bv[4];
    #pragma unroll
    for (int i=0;i<4;i++){
      av[i] = *(const b16x8*)&As[(wm*64 + i*16 + fr)*32 + fq*8];
      bv[i] = *(const b16x8*)&Bs[(wn*64 + i*16 + fr)*32 + fq*8];
    }
    #pragma unroll
    for (int i=0;i<4;i++)
      #pragma unroll
      for (int j=0;j<4;j++)
        acc[i][j] = __builtin_amdgcn_mfma_f32_16x16x32_bf16(av[i], bv[j], acc[i][j], 0, 0, 0);
    __syncthreads();
  }

  #pragma unroll
  for (int i=0;i<4;i++){
    #pragma unroll
    for (int j=0;j<4;j++){
      #pragma unroll
      for (int r=0;r<4;r++){
        const long m = m0 + wm*64 + i*16 + fq*4 + r;   // C row = quad*4+reg
        const long n = n0 + wn*64 + j*16 + fr;         // C col = lane&15
        float v = acc[i][j][r];
        if (MODE == 0){
          v = v > 0.f ? v : 0.f;
          O0[m*DH + n] = f2bf(v);
        } else {
          if (n < DH) O0[m*DH + n]      = f2bf(v + b0[n]);
          else        O1[m*DH + (n-DH)] = f2bf(v + b1[n-DH]);
        }
      }
    }
  }
}

// ---------------- phase2: aggr2 + self + relu -> x2 ----------------
__global__ __launch_bounds__(128) void k_phase2(const u16* __restrict__ hm,
                                                const u16* __restrict__ sfx,
                                                const int* __restrict__ srcp,
                                                const int* __restrict__ starts,
                                                float* __restrict__ x2){
  const int i = blockIdx.x, t = threadIdx.x;
  float a[6] = {0,0,0,0,0,0};
  const int e0 = starts[i], e1 = starts[i+1];
  for (int p=e0; p<e1; ++p){
    const int s = srcp[p];
    const u16* hr = hm + (long)s*DH;
    #pragma unroll
    for (int j=0;j<6;j++) a[j] += bf2f(hr[t + 128*j]);
  }
  #pragma unroll
  for (int j=0;j<6;j++){
    const int c = t + 128*j;
    float v = a[j] + bf2f(sfx[(long)i*DH + c]);
    x2[(long)i*DH + c] = v > 0.f ? v : 0.f;
  }
}

// ---------------- mean-pool reduce ----------------
__global__ __launch_bounds__(256) void k_reduce(const float* __restrict__ x2,
                                                float* __restrict__ pooled){
  const int b = blockIdx.x, t = threadIdx.x;
  float s0=0.f, s1=0.f, s2=0.f;
  const int r0 = b*64;
  for (int r=r0; r<r0+64; ++r){
    const float* row = x2 + (long)r*DH;
    s0 += row[t]; s1 += row[t+256]; s2 += row[t+512];
  }
  atomicAdd(&pooled[t],     s0);
  atomicAdd(&pooled[t+256], s1);
  atomicAdd(&pooled[t+512], s2);
}

__global__ __launch_bounds__(256) void k_final(const float* __restrict__ pooled,
                                               const float* __restrict__ oW,
                                               const float* __restrict__ ob,
                                               float* __restrict__ out){
  __shared__ float red[256];
  const int t = threadIdx.x;
  for (int c=0;c<5;c++){
    float p = 0.f;
    for (int h=t; h<DH; h+=256) p += pooled[h]*oW[c*DH + h];
    red[t] = p; __syncthreads();
    for (int o=128;o;o>>=1){ if (t<o) red[t]+=red[t+o]; __syncthreads(); }
    if (t == 0) out[c] = red[0]*(1.f/(float)NN) + ob[c];
    __syncthreads();
  }
}

// ---------------- launch ----------------
extern "C" void kernel_launch(void* const* d_in, const int* in_sizes, int n_in,
                              void* d_out, int out_size, void* d_ws, size_t ws_size,
                              hipStream_t stream)
{
  (void)in_sizes; (void)n_in; (void)out_size; (void)ws_size;
  const float* x     = (const float*)d_in[0];
  const int*   ei    = (const int*)  d_in[1];   // [2][E]: row0=src, row1=dst
  const int*   et    = (const int*)  d_in[2];
  const float* relW  = (const float*)d_in[3];
  const float* relb  = (const float*)d_in[4];
  const float* nc    = (const float*)d_in[5];
  const float* linW  = (const float*)d_in[6];
  const float* linb  = (const float*)d_in[7];
  const float* selfW = (const float*)d_in[8];
  const float* selfb = (const float*)d_in[9];
  const float* outW  = (const float*)d_in[10];
  const float* outb  = (const float*)d_in[11];
  float* out = (float*)d_out;

  // workspace layout (256B aligned); hm/selfx/x2 alias S (dead after gemm1)
  u8* w = (u8*)d_ws;
  int*   counts = (int*)(w + 0);              // 64 KB
  int*   starts = (int*)(w + 65536);          // 16385*4
  int*   cursor = (int*)(w + 131328);         // 64 KB
  int*   srcp   = (int*)(w + 196864);         // 1 MB
  int*   dstp   = (int*)(w + 1245440);        // 1 MB
  int*   rp     = (int*)(w + 2294016);        // 1 MB
  float* normp  = (float*)(w + 3342592);      // 1 MB
  u16*   Wst    = (u16*)(w + 4391168);        // 768*3488*2  = 5.36 MB
  u16*   WB     = (u16*)(w + 9748736);        // 1536*768*2  = 2.36 MB
  u16*   x1     = (u16*)(w + 12108032);       // 16384*768*2 = 25.2 MB
  float* pooled = (float*)(w + 37273856);     // 3 KB
  u16*   S      = (u16*)(w + 37276928);       // 16384*3488*2 = 114.3 MB
  u16*   hm     = S;                          // alias: 25.2 MB
  u16*   sfx    = (u16*)(w + 37276928 + 25165824);
  float* x2     = (float*)(w + 37276928 + 50331648);  // 50.3 MB (fits in S)

  const int* esrc = ei;
  const int* edst = ei + EE;

  hipMemsetAsync(counts, 0, NN*sizeof(int), stream);
  hipMemsetAsync(pooled, 0, DH*sizeof(float), stream);

  k_count <<<EE/256, 256, 0, stream>>>(edst, counts);
  k_scan  <<<1, 1024, 0, stream>>>(counts, starts, cursor);
  k_place <<<EE/256, 256, 0, stream>>>(esrc, edst, et, cursor, srcp, dstp, rp);
  k_convW1<<<dim3(14, DH), 256, 0, stream>>>(relW, relb, Wst);
  k_convW2<<<(2*DH*DH)/256, 256, 0, stream>>>(linW, selfW, WB);
  k_dots  <<<EE/4, 256, 0, stream>>>(x, srcp, dstp, rp, nc, normp);
  k_phase1b<<<NN, 128, 0, stream>>>(x, srcp, rp, normp, starts, S);
  k_gemm_bt<0><<<dim3(DH/128, NN/128), 256, 0, stream>>>(
      S, Wst, NN, DH, KS, x1, (u16*)nullptr, (const float*)nullptr, (const float*)nullptr);
  k_gemm_bt<1><<<dim3(2*DH/128, NN/128), 256, 0, stream>>>(
      x1, WB, NN, 2*DH, DH, hm, sfx, linb, selfb);
  k_phase2<<<NN, 128, 0, stream>>>(hm, sfx, srcp, starts, x2);
  k_reduce<<<NN/64, 256, 0, stream>>>(x2, pooled);
  k_final <<<1, 256, 0, stream>>>(pooled, outW, outb, out);
}

// Round 3
// 536.391 us; speedup vs baseline: 1.1081x; 1.0452x over previous
//
#include <hip/hip_runtime.h>

typedef unsigned char  u8;
typedef unsigned short u16;
typedef unsigned int   u32;

#define NN   16384     // nodes
#define EE   262144    // edges
#define RR   9         // relations
#define DIN  384
#define DH   768
#define KSU  3456      // RR*DIN
#define KS   3488      // KSU + 9 cnt cols + pad to 32

typedef float  f32x4 __attribute__((ext_vector_type(4)));
typedef float  f32x2 __attribute__((ext_vector_type(2)));
typedef __bf16 b16x8 __attribute__((ext_vector_type(8)));

__device__ __forceinline__ u16 f2bf(float f){
  u32 u = __builtin_bit_cast(u32, f);
  u += 0x7fffu + ((u >> 16) & 1u);          // RNE
  return (u16)(u >> 16);
}
__device__ __forceinline__ float bf2f(u16 h){
  u32 u = ((u32)h) << 16;
  return __builtin_bit_cast(float, u);
}
// async global->LDS, 16B per lane; LDS dest = wave-uniform base + lane*16
__device__ __forceinline__ void gll16(const void* g, void* l){
  __builtin_amdgcn_global_load_lds((const __attribute__((address_space(1))) void*)g,
                                   (__attribute__((address_space(3))) void*)l, 16, 0, 0);
}

// ---------------- CSR build ----------------
__global__ void k_count(const int* __restrict__ dst, int* __restrict__ counts){
  const int e = blockIdx.x*256 + threadIdx.x;
  if (e < EE) atomicAdd(&counts[dst[e]], 1);
}

__global__ __launch_bounds__(1024) void k_scan(const int* __restrict__ counts,
                                               int* __restrict__ starts,
                                               int* __restrict__ cursor){
  __shared__ int tot[1024];
  const int t = threadIdx.x;
  int loc[16]; int s = 0;
  #pragma unroll
  for (int j=0;j<16;j++){ loc[j] = counts[t*16+j]; s += loc[j]; }
  tot[t] = s;
  __syncthreads();
  for (int o=1;o<1024;o<<=1){
    int v = (t>=o) ? tot[t-o] : 0;
    __syncthreads();
    tot[t] += v;
    __syncthreads();
  }
  int run = tot[t] - s;  // exclusive prefix
  #pragma unroll
  for (int j=0;j<16;j++){ starts[t*16+j] = run; cursor[t*16+j] = run; run += loc[j]; }
  if (t == 1023) starts[NN] = run;
}

// scatter edges into CSR order; emit pre-gathered src/rtype arrays
__global__ void k_place(const int* __restrict__ src, const int* __restrict__ dst,
                        const int* __restrict__ et, int* __restrict__ cursor,
                        int* __restrict__ srcp, int* __restrict__ rp){
  const int e = blockIdx.x*256 + threadIdx.x;
  if (e < EE){
    const int p = atomicAdd(&cursor[dst[e]], 1);
    srcp[p] = src[e];
    rp[p]   = et[e];
  }
}

// ---------------- weight conversion to bf16 ----------------
__global__ void k_convW1(const float* __restrict__ rW, const float* __restrict__ rb,
                         u16* __restrict__ Wst){
  const int hh = blockIdx.y;
  const int k  = blockIdx.x*256 + threadIdx.x;
  if (k >= KS) return;
  float v;
  if (k < KSU){ const int r = k / DIN; const int d = k - r*DIN;
                v = rW[((long)r*DH + hh)*DIN + d]; }
  else if (k < KSU + RR){ const int r = k - KSU; v = rb[(long)r*DH + hh]; }
  else v = 0.f;
  Wst[(long)hh*KS + k] = f2bf(v);
}

__global__ void k_convW2(const float* __restrict__ lW, const float* __restrict__ sW,
                         u16* __restrict__ WB){
  const int idx = blockIdx.x*256 + threadIdx.x;  // exactly 1179648 threads
  const float v = (idx < DH*DH) ? lW[idx] : sW[idx - DH*DH];
  WB[idx] = f2bf(v);
}

// ---------------- phase1 fused: one wave per dst node, VGPR accumulators ----
// s[i, r*384+d] = sum_{p in seg(i)} (dot(x[i],x[srcp])/nc[r]) * x[srcp, d]
// s[i, 3456+r]  = sum norm ; rest of row = 0
__global__ __launch_bounds__(64) void k_phase1f(const float* __restrict__ x,
                                                const int* __restrict__ srcp,
                                                const int* __restrict__ rp,
                                                const float* __restrict__ nc,
                                                const int* __restrict__ starts,
                                                u16* __restrict__ s){
  const int i = blockIdx.x, l = threadIdx.x;
  const float* xdp = x + (long)i*DIN;
  const f32x2 xd0 = *(const f32x2*)(xdp + 2*l);
  const f32x2 xd1 = *(const f32x2*)(xdp + 128 + 2*l);
  const f32x2 xd2 = *(const f32x2*)(xdp + 256 + 2*l);
  float ncv[RR];
  #pragma unroll
  for (int r=0;r<RR;r++) ncv[r] = 1.0f / nc[r];
  float acc[RR][6];
  float cacc[RR];
  #pragma unroll
  for (int r=0;r<RR;r++){
    cacc[r] = 0.f;
    #pragma unroll
    for (int j=0;j<6;j++) acc[r][j] = 0.f;
  }
  const int e0 = starts[i], e1 = starts[i+1];
  f32x2 n0 = {0.f,0.f}, n1 = {0.f,0.f}, n2 = {0.f,0.f};
  int rn = 0;
  if (e0 < e1){
    const float* xs = x + (long)srcp[e0]*DIN;
    n0 = *(const f32x2*)(xs + 2*l);
    n1 = *(const f32x2*)(xs + 128 + 2*l);
    n2 = *(const f32x2*)(xs + 256 + 2*l);
    rn = rp[e0];
  }
  for (int p=e0; p<e1; ++p){
    const f32x2 c0 = n0, c1 = n1, c2 = n2;
    const int r = rn;
    if (p+1 < e1){                       // prefetch next edge's row
      const float* xs = x + (long)srcp[p+1]*DIN;
      n0 = *(const f32x2*)(xs + 2*l);
      n1 = *(const f32x2*)(xs + 128 + 2*l);
      n2 = *(const f32x2*)(xs + 256 + 2*l);
      rn = rp[p+1];
    }
    float part = xd0.x*c0.x + xd0.y*c0.y + xd1.x*c1.x + xd1.y*c1.y
               + xd2.x*c2.x + xd2.y*c2.y;
    #pragma unroll
    for (int o=32;o;o>>=1) part += __shfl_xor(part, o);
    #define UPD(R) { const float nm = part*ncv[R]; cacc[R] += nm; \
      acc[R][0] += nm*c0.x; acc[R][1] += nm*c0.y; acc[R][2] += nm*c1.x; \
      acc[R][3] += nm*c1.y; acc[R][4] += nm*c2.x; acc[R][5] += nm*c2.y; }
    switch (r){                           // wave-uniform branch
      case 0: UPD(0); break; case 1: UPD(1); break; case 2: UPD(2); break;
      case 3: UPD(3); break; case 4: UPD(4); break; case 5: UPD(5); break;
      case 6: UPD(6); break; case 7: UPD(7); break; default: UPD(8); break;
    }
    #undef UPD
  }
  u16* srow = s + (long)i*KS;
  #pragma unroll
  for (int r=0;r<RR;r++){
    #pragma unroll
    for (int seg=0;seg<3;seg++){
      const u32 pk = (u32)f2bf(acc[r][seg*2]) | ((u32)f2bf(acc[r][seg*2+1]) << 16);
      ((u32*)(srow + r*DIN + seg*128))[l] = pk;   // cols seg*128 + {2l, 2l+1}
    }
  }
  float cv = 0.f;
  #pragma unroll
  for (int r=0;r<RR;r++) cv = (l == r) ? cacc[r] : cv;
  if (l < 32) srow[KSU + l] = f2bf(l < RR ? cv : 0.f);
}

// ---------------- m97-style bf16 GEMM: C = A * B^T (both K-major) ----------------
// grid: x = M-tile (fast), y = N-tile  -> same-A blocks land on same XCD (id%8)
// MODE 0: O0 = relu(C) bf16, stride DH           (gemm1: x1)
// MODE 1: n<768 -> O0 = C+b0[n]; else O1 = C+b1  (gemm2: hm / selfx)
template<int MODE>
__global__ __launch_bounds__(256, 2)
void k_gemm_bt(const u16* __restrict__ A, const u16* __restrict__ B,
               int M, int N, int K,
               u16* __restrict__ O0, u16* __restrict__ O1,
               const float* __restrict__ b0, const float* __restrict__ b1)
{
  __shared__ __align__(16) u16 As[128*32];
  __shared__ __align__(16) u16 Bs[128*32];
  const int t  = threadIdx.x;
  const int wv = t >> 6;
  const int ln = t & 63;
  const int wm = wv >> 1, wn = wv & 1;
  const long m0 = (long)blockIdx.x * 128;
  const long n0 = (long)blockIdx.y * 128;

  const int srow  = ln >> 2;         // staging: lane -> row within 16-row segment
  const int skcol = (ln & 3) * 8;    // k element offset (8 bf16 = 16B)

  f32x4 acc[4][4];
  #pragma unroll
  for (int i=0;i<4;i++)
    #pragma unroll
    for (int j=0;j<4;j++) acc[i][j] = {0.f,0.f,0.f,0.f};

  const int fr = ln & 15, fq = ln >> 4;
  const int nk = K >> 5;
  for (int kb=0; kb<nk; ++kb){
    const long k0 = (long)kb * 32;
    #pragma unroll
    for (int q=0;q<2;q++){
      const int seg = wv*2 + q;
      const int row = seg*16 + srow;
      gll16(A + (m0 + row)*(long)K + k0 + skcol, &As[seg*512]);
      gll16(B + (n0 + row)*(long)K + k0 + skcol, &Bs[seg*512]);
    }
    __syncthreads();
    b16x8 av[4], bv[4];
    #pragma unroll
    for (int i=0;i<4;i++){
      av[i] = *(const b16x8*)&As[(wm*64 + i*16 + fr)*32 + fq*8];
      bv[i] = *(const b16x8*)&Bs[(wn*64 + i*16 + fr)*32 + fq*8];
    }
    #pragma unroll
    for (int i=0;i<4;i++)
      #pragma unroll
      for (int j=0;j<4;j++)
        acc[i][j] = __builtin_amdgcn_mfma_f32_16x16x32_bf16(av[i], bv[j], acc[i][j], 0, 0, 0);
    __syncthreads();
  }

  #pragma unroll
  for (int i=0;i<4;i++){
    #pragma unroll
    for (int j=0;j<4;j++){
      #pragma unroll
      for (int r=0;r<4;r++){
        const long m = m0 + wm*64 + i*16 + fq*4 + r;   // C row = quad*4+reg
        const long n = n0 + wn*64 + j*16 + fr;         // C col = lane&15
        float v = acc[i][j][r];
        if (MODE == 0){
          v = v > 0.f ? v : 0.f;
          O0[m*DH + n] = f2bf(v);
        } else {
          if (n < DH) O0[m*DH + n]      = f2bf(v + b0[n]);
          else        O1[m*DH + (n-DH)] = f2bf(v + b1[n-DH]);
        }
      }
    }
  }
}

// ---------------- phase2: aggr2 + self + relu -> x2 ----------------
__global__ __launch_bounds__(128) void k_phase2(const u16* __restrict__ hm,
                                                const u16* __restrict__ sfx,
                                                const int* __restrict__ srcp,
                                                const int* __restrict__ starts,
                                                float* __restrict__ x2){
  const int i = blockIdx.x, t = threadIdx.x;
  float a[6] = {0,0,0,0,0,0};
  const int e0 = starts[i], e1 = starts[i+1];
  for (int p=e0; p<e1; ++p){
    const int s = srcp[p];
    const u16* hr = hm + (long)s*DH;
    #pragma unroll
    for (int j=0;j<6;j++) a[j] += bf2f(hr[t + 128*j]);
  }
  #pragma unroll
  for (int j=0;j<6;j++){
    const int c = t + 128*j;
    float v = a[j] + bf2f(sfx[(long)i*DH + c]);
    x2[(long)i*DH + c] = v > 0.f ? v : 0.f;
  }
}

// ---------------- mean-pool reduce ----------------
__global__ __launch_bounds__(256) void k_reduce(const float* __restrict__ x2,
                                                float* __restrict__ pooled){
  const int b = blockIdx.x, t = threadIdx.x;
  float s0=0.f, s1=0.f, s2=0.f;
  const int r0 = b*64;
  for (int r=r0; r<r0+64; ++r){
    const float* row = x2 + (long)r*DH;
    s0 += row[t]; s1 += row[t+256]; s2 += row[t+512];
  }
  atomicAdd(&pooled[t],     s0);
  atomicAdd(&pooled[t+256], s1);
  atomicAdd(&pooled[t+512], s2);
}

__global__ __launch_bounds__(256) void k_final(const float* __restrict__ pooled,
                                               const float* __restrict__ oW,
                                               const float* __restrict__ ob,
                                               float* __restrict__ out){
  __shared__ float red[256];
  const int t = threadIdx.x;
  for (int c=0;c<5;c++){
    float p = 0.f;
    for (int h=t; h<DH; h+=256) p += pooled[h]*oW[c*DH + h];
    red[t] = p; __syncthreads();
    for (int o=128;o;o>>=1){ if (t<o) red[t]+=red[t+o]; __syncthreads(); }
    if (t == 0) out[c] = red[0]*(1.f/(float)NN) + ob[c];
    __syncthreads();
  }
}

// ---------------- launch ----------------
extern "C" void kernel_launch(void* const* d_in, const int* in_sizes, int n_in,
                              void* d_out, int out_size, void* d_ws, size_t ws_size,
                              hipStream_t stream)
{
  (void)in_sizes; (void)n_in; (void)out_size; (void)ws_size;
  const float* x     = (const float*)d_in[0];
  const int*   ei    = (const int*)  d_in[1];   // [2][E]: row0=src, row1=dst
  const int*   et    = (const int*)  d_in[2];
  const float* relW  = (const float*)d_in[3];
  const float* relb  = (const float*)d_in[4];
  const float* nc    = (const float*)d_in[5];
  const float* linW  = (const float*)d_in[6];
  const float* linb  = (const float*)d_in[7];
  const float* selfW = (const float*)d_in[8];
  const float* selfb = (const float*)d_in[9];
  const float* outW  = (const float*)d_in[10];
  const float* outb  = (const float*)d_in[11];
  float* out = (float*)d_out;

  // workspace layout (256B aligned); hm/selfx/x2 alias S (dead after gemm1)
  u8* w = (u8*)d_ws;
  int*   counts = (int*)(w + 0);              // 64 KB
  int*   starts = (int*)(w + 65536);          // 16385*4
  int*   cursor = (int*)(w + 131328);         // 64 KB
  int*   srcp   = (int*)(w + 196864);         // 1 MB
  int*   rp     = (int*)(w + 2294016);        // 1 MB
  u16*   Wst    = (u16*)(w + 4391168);        // 768*3488*2  = 5.36 MB
  u16*   WB     = (u16*)(w + 9748736);        // 1536*768*2  = 2.36 MB
  u16*   x1     = (u16*)(w + 12108032);       // 16384*768*2 = 25.2 MB
  float* pooled = (float*)(w + 37273856);     // 3 KB
  u16*   S      = (u16*)(w + 37276928);       // 16384*3488*2 = 114.3 MB
  u16*   hm     = S;                          // alias: 25.2 MB
  u16*   sfx    = (u16*)(w + 37276928 + 25165824);
  float* x2     = (float*)(w + 37276928 + 50331648);  // 50.3 MB (fits in S)

  const int* esrc = ei;
  const int* edst = ei + EE;

  hipMemsetAsync(counts, 0, NN*sizeof(int), stream);
  hipMemsetAsync(pooled, 0, DH*sizeof(float), stream);

  k_count <<<EE/256, 256, 0, stream>>>(edst, counts);
  k_scan  <<<1, 1024, 0, stream>>>(counts, starts, cursor);
  k_place <<<EE/256, 256, 0, stream>>>(esrc, edst, et, cursor, srcp, rp);
  k_convW1<<<dim3(14, DH), 256, 0, stream>>>(relW, relb, Wst);
  k_convW2<<<(2*DH*DH)/256, 256, 0, stream>>>(linW, selfW, WB);
  k_phase1f<<<NN, 64, 0, stream>>>(x, srcp, rp, nc, starts, S);
  k_gemm_bt<0><<<dim3(NN/128, DH/128), 256, 0, stream>>>(
      S, Wst, NN, DH, KS, x1, (u16*)nullptr, (const float*)nullptr, (const float*)nullptr);
  k_gemm_bt<1><<<dim3(NN/128, 2*DH/128), 256, 0, stream>>>(
      x1, WB, NN, 2*DH, DH, hm, sfx, linb, selfb);
  k_phase2<<<NN, 128, 0, stream>>>(hm, sfx, srcp, starts, x2);
  k_reduce<<<NN/64, 256, 0, stream>>>(x2, pooled);
  k_final <<<1, 256, 0, stream>>>(pooled, outW, outb, out);
}